// Round 1
// baseline (619.126 us; speedup 1.0000x reference)
//
#include <hip/hip_runtime.h>

// GRUAdder: B=1048576 independent sequences, T=4 steps, I=2 inputs, H=16 hidden.
// One thread per batch element; whole recurrence in registers, fully unrolled.
// Weights (~4KB) are uniform across threads -> compiler should emit s_load
// (scalar cache) since all indices are compile-time constants off __restrict__
// read-only pointers.

constexpr long long Bn = 1048576;
constexpr int Tn = 4;
constexpr int Hn = 16;

__device__ __forceinline__ float sigm_f(float x) {
    // 1 / (1 + e^-x); v_exp_f32 + v_rcp_f32
    return __builtin_amdgcn_rcpf(1.0f + __expf(-x));
}
__device__ __forceinline__ float tanh_f(float x) {
    // tanh(x) = 1 - 2/(e^{2x}+1)
    return 1.0f - 2.0f * __builtin_amdgcn_rcpf(1.0f + __expf(2.0f * x));
}

__global__ void gru_adder_kernel(
    const float* __restrict__ x_bits,   // [B, 4, 2]
    const float* __restrict__ w_ih,     // [48, 2]
    const float* __restrict__ w_hh,     // [48, 16]
    const float* __restrict__ b_ih,     // [48]
    const float* __restrict__ b_hh,     // [48]
    const float* __restrict__ w_sum,    // [1, 16]
    const float* __restrict__ b_sum,    // [1]
    const float* __restrict__ w_carry,  // [1, 16]
    const float* __restrict__ b_carry,  // [1]
    float* __restrict__ out)            // [64B | 4B | B | 5B] floats
{
    const long long b = (long long)blockIdx.x * blockDim.x + threadIdx.x;
    if (b >= Bn) return;

    // Load this sequence's 8 input floats (32B-aligned, two float4).
    const float4* xp = (const float4*)(x_bits + b * 8);
    const float4 xv0 = xp[0];
    const float4 xv1 = xp[1];
    float xs[8] = {xv0.x, xv0.y, xv0.z, xv0.w, xv1.x, xv1.y, xv1.z, xv1.w};

    float h[Hn];
    float sums[Tn];

    // ---- t = 0: h == 0, so gh == b_hh (skip the 768 h@W_hh FMAs) ----
    {
        const float x0 = xs[0], x1 = xs[1];
#pragma unroll
        for (int j = 0; j < Hn; ++j) {
            const float ir  = fmaf(x1, w_ih[(j)      * 2 + 1], fmaf(x0, w_ih[(j)      * 2], b_ih[j]));
            const float iz  = fmaf(x1, w_ih[(16 + j) * 2 + 1], fmaf(x0, w_ih[(16 + j) * 2], b_ih[16 + j]));
            const float inn = fmaf(x1, w_ih[(32 + j) * 2 + 1], fmaf(x0, w_ih[(32 + j) * 2], b_ih[32 + j]));
            const float r = sigm_f(ir + b_hh[j]);
            const float z = sigm_f(iz + b_hh[16 + j]);
            const float n = tanh_f(fmaf(r, b_hh[32 + j], inn));
            h[j] = n - z * n;  // (1-z)*n + z*0
        }
        // store hidden_table[b][0][:]
        float4* hp = (float4*)(out + (b * 4 + 0) * 16);
        hp[0] = make_float4(h[0], h[1], h[2], h[3]);
        hp[1] = make_float4(h[4], h[5], h[6], h[7]);
        hp[2] = make_float4(h[8], h[9], h[10], h[11]);
        hp[3] = make_float4(h[12], h[13], h[14], h[15]);
        float s = b_sum[0];
#pragma unroll
        for (int k = 0; k < Hn; ++k) s = fmaf(h[k], w_sum[k], s);
        sums[0] = s;
    }

    // ---- t = 1..3 ----
#pragma unroll
    for (int t = 1; t < Tn; ++t) {
        const float x0 = xs[2 * t], x1 = xs[2 * t + 1];
        float hn[Hn];
#pragma unroll
        for (int j = 0; j < Hn; ++j) {
            const float ir  = fmaf(x1, w_ih[(j)      * 2 + 1], fmaf(x0, w_ih[(j)      * 2], b_ih[j]));
            const float iz  = fmaf(x1, w_ih[(16 + j) * 2 + 1], fmaf(x0, w_ih[(16 + j) * 2], b_ih[16 + j]));
            const float inn = fmaf(x1, w_ih[(32 + j) * 2 + 1], fmaf(x0, w_ih[(32 + j) * 2], b_ih[32 + j]));
            float hr = b_hh[j];
            float hz = b_hh[16 + j];
            float hg = b_hh[32 + j];
#pragma unroll
            for (int k = 0; k < Hn; ++k) {
                const float hk = h[k];
                hr = fmaf(hk, w_hh[(j)      * 16 + k], hr);
                hz = fmaf(hk, w_hh[(16 + j) * 16 + k], hz);
                hg = fmaf(hk, w_hh[(32 + j) * 16 + k], hg);
            }
            const float r = sigm_f(ir + hr);
            const float z = sigm_f(iz + hz);
            const float n = tanh_f(fmaf(r, hg, inn));
            hn[j] = fmaf(z, h[j] - n, n);  // (1-z)*n + z*h
        }
#pragma unroll
        for (int j = 0; j < Hn; ++j) h[j] = hn[j];

        float4* hp = (float4*)(out + (b * 4 + t) * 16);
        hp[0] = make_float4(h[0], h[1], h[2], h[3]);
        hp[1] = make_float4(h[4], h[5], h[6], h[7]);
        hp[2] = make_float4(h[8], h[9], h[10], h[11]);
        hp[3] = make_float4(h[12], h[13], h[14], h[15]);

        float s = b_sum[0];
#pragma unroll
        for (int k = 0; k < Hn; ++k) s = fmaf(h[k], w_sum[k], s);
        sums[t] = s;
    }

    // carry logit from final h
    float c = b_carry[0];
#pragma unroll
    for (int k = 0; k < Hn; ++k) c = fmaf(h[k], w_carry[k], c);

    // sum_logits [B,4] at offset 64*B (16B-aligned per thread)
    float4* sp = (float4*)(out + 64ll * Bn + b * 4);
    sp[0] = make_float4(sums[0], sums[1], sums[2], sums[3]);

    // carry_logit [B,1] at offset 68*B
    out[68ll * Bn + b] = c;

    // output_logits [B,5] at offset 69*B (20B stride -> scalar stores)
    float* ol = out + 69ll * Bn + b * 5;
    ol[0] = sums[0];
    ol[1] = sums[1];
    ol[2] = sums[2];
    ol[3] = sums[3];
    ol[4] = c;
}

extern "C" void kernel_launch(void* const* d_in, const int* in_sizes, int n_in,
                              void* d_out, int out_size, void* d_ws, size_t ws_size,
                              hipStream_t stream) {
    const float* x_bits  = (const float*)d_in[0];
    const float* w_ih    = (const float*)d_in[1];
    const float* w_hh    = (const float*)d_in[2];
    const float* b_ih    = (const float*)d_in[3];
    const float* b_hh    = (const float*)d_in[4];
    const float* w_sum   = (const float*)d_in[5];
    const float* b_sum   = (const float*)d_in[6];
    const float* w_carry = (const float*)d_in[7];
    const float* b_carry = (const float*)d_in[8];
    float* out = (float*)d_out;

    const int block = 256;
    const int grid = (int)((Bn + block - 1) / block);  // 4096
    gru_adder_kernel<<<grid, block, 0, stream>>>(
        x_bits, w_ih, w_hh, b_ih, b_hh, w_sum, b_sum, w_carry, b_carry, out);
}